// Round 4
// baseline (80.992 us; speedup 1.0000x reference)
//
#include <hip/hip_runtime.h>
#include <math.h>

#define N_PIX 8192      // 2*64*64
#define D 64
#define HW 4096         // h*w
#define BSTRIDE 262144  // d*h*w
#define C1 14.4269504088896340736f   // 10 * log2(e); also = max |sim|*log2e since |dot|<=1
#define NSEG 8
#define SEGCOLS (N_PIX / NSEG)       // 1024 cols per segment
#define NTILE (SEGCOLS / 16)         // 64 col-tiles per segment

typedef __attribute__((ext_vector_type(8))) short short8;   // 8 bf16 = 4 VGPR
typedef __attribute__((ext_vector_type(4))) float f32x4;

__device__ inline ushort f2bf(float x) {   // fp32 -> bf16 RNE
    uint u = __float_as_uint(x);
    return (ushort)((u + 0x7FFFu + ((u >> 16) & 1u)) >> 16);
}
__device__ inline float bflo(uint u) { return __uint_as_float(u << 16); }
__device__ inline float bfhi(uint u) { return __uint_as_float(u & 0xFFFF0000u); }

// ---------- K1: transpose + L2-normalize + convert to bf16 rows (N,64) ----------
__global__ __launch_bounds__(256) void knorm(const float* __restrict__ z1,
                                             const float* __restrict__ z2,
                                             ushort* __restrict__ z1b,
                                             ushort* __restrict__ z2b) {
    int gid = blockIdx.x * 256 + threadIdx.x;   // 0..16383
    int t = gid >> 13;
    int n = gid & (N_PIX - 1);
    const float* src = t ? z2 : z1;
    ushort* dst = t ? z2b : z1b;
    int b = n >> 12;
    int p = n & 4095;
    const float* base = src + b * BSTRIDE + p;
    float v[D];
    float ss = 0.f;
#pragma unroll
    for (int c = 0; c < D; ++c) { v[c] = base[c * HW]; ss += v[c] * v[c]; }
    float inv = 1.0f / fmaxf(sqrtf(ss), 1e-12f);
    uint* o = (uint*)(dst + (size_t)n * D);
#pragma unroll
    for (int c2 = 0; c2 < D / 2; ++c2) {
        uint w = (uint)f2bf(v[2 * c2] * inv) | ((uint)f2bf(v[2 * c2 + 1] * inv) << 16);
        o[c2] = w;
    }
}

// ---------- K2: MFMA sim tiles + fixed-shift exp accumulation ----------
// grid (128 row-blocks of 64, NSEG col-segments), 256 thr = 4 waves,
// wave w owns rows rbase..rbase+15; per-row partial sum of 2^{(dot-1)*C1}.
__global__ __launch_bounds__(256) void ksim(const ushort* __restrict__ z1b,
                                            const ushort* __restrict__ z2b,
                                            float* __restrict__ ps) {
    int tid = threadIdx.x;
    int wave = tid >> 6, lane = tid & 63;
    int lrow = lane & 15;        // operand row index within 16
    int lk = lane >> 4;          // k-chunk 0..3 (8 bf16 each)
    int rbase = blockIdx.x * 64 + wave * 16;
    int seg = blockIdx.y;
    int jbase = seg * SEGCOLS;

    // A fragments: z1 row (rbase+lrow), k = lk*8..+7 and 32+lk*8..+7
    const ushort* arow = z1b + (size_t)(rbase + lrow) * D + lk * 8;
    short8 a0 = *(const short8*)arow;
    short8 a1 = *(const short8*)(arow + 32);

    float s0 = 0.f, s1 = 0.f, s2 = 0.f, s3 = 0.f;

    const ushort* bptr = z2b + (size_t)(jbase + lrow) * D + lk * 8;
    short8 b0 = *(const short8*)bptr;
    short8 b1 = *(const short8*)(bptr + 32);

    for (int tt = 0; tt < NTILE; ++tt) {
        short8 nb0 = b0, nb1 = b1;
        if (tt + 1 < NTILE) {                       // prefetch next 16 z2 rows
            const ushort* np = bptr + (size_t)(tt + 1) * 16 * D;
            nb0 = *(const short8*)np;
            nb1 = *(const short8*)(np + 32);
        }
        f32x4 acc = {0.f, 0.f, 0.f, 0.f};
        acc = __builtin_amdgcn_mfma_f32_16x16x32_bf16(a0, b0, acc, 0, 0, 0);
        acc = __builtin_amdgcn_mfma_f32_16x16x32_bf16(a1, b1, acc, 0, 0, 0);
        // C/D: col = lane&15 (z2 row), row = lk*4 + reg (z1 row) [m89]
        s0 += exp2f(fmaf(acc[0], C1, -C1));
        s1 += exp2f(fmaf(acc[1], C1, -C1));
        s2 += exp2f(fmaf(acc[2], C1, -C1));
        s3 += exp2f(fmaf(acc[3], C1, -C1));
        b0 = nb0; b1 = nb1;
    }

    // reduce over the 16 lanes sharing lk (they hold different cols, same 4 rows)
#pragma unroll
    for (int off = 1; off <= 8; off <<= 1) {
        s0 += __shfl_xor(s0, off);
        s1 += __shfl_xor(s1, off);
        s2 += __shfl_xor(s2, off);
        s3 += __shfl_xor(s3, off);
    }
    if (lrow == 0) {
        int r0 = rbase + lk * 4;
        ps[(size_t)(r0 + 0) * NSEG + seg] = s0;
        ps[(size_t)(r0 + 1) * NSEG + seg] = s1;
        ps[(size_t)(r0 + 2) * NSEG + seg] = s2;
        ps[(size_t)(r0 + 3) * NSEG + seg] = s3;
    }
}

// ---------- K3: combine partials + diag -> per-row loss ----------
__global__ __launch_bounds__(256) void kfinal(const ushort* __restrict__ z1b,
                                              const ushort* __restrict__ z2b,
                                              const float* __restrict__ ps,
                                              float* __restrict__ rowval) {
    int row = blockIdx.x * 256 + threadIdx.x;
    float s = 0.f;
#pragma unroll
    for (int k = 0; k < NSEG; ++k) s += ps[(size_t)row * NSEG + k];
    // lse = ln( sum e^{10 dot} ) = 10 + ln( sum 2^{(dot-1)*C1} )
    const uint4* xp = (const uint4*)(z1b + (size_t)row * D);
    const uint4* yp = (const uint4*)(z2b + (size_t)row * D);
    float d = 0.f;
#pragma unroll
    for (int q = 0; q < 8; ++q) {
        uint4 x = xp[q], y = yp[q];
        d = fmaf(bflo(x.x), bflo(y.x), d); d = fmaf(bfhi(x.x), bfhi(y.x), d);
        d = fmaf(bflo(x.y), bflo(y.y), d); d = fmaf(bfhi(x.y), bfhi(y.y), d);
        d = fmaf(bflo(x.z), bflo(y.z), d); d = fmaf(bfhi(x.z), bfhi(y.z), d);
        d = fmaf(bflo(x.w), bflo(y.w), d); d = fmaf(bfhi(x.w), bfhi(y.w), d);
    }
    rowval[row] = 10.0f + logf(s) - 10.0f * d;
}

// ---------- K4: mean ----------
__global__ __launch_bounds__(256) void kreduce(const float* __restrict__ rowval,
                                               float* __restrict__ out) {
    __shared__ float wsum[4];
    int tid = threadIdx.x;
    float s = 0.f;
    for (int k = tid; k < N_PIX; k += 256) s += rowval[k];
#pragma unroll
    for (int off = 32; off > 0; off >>= 1) s += __shfl_down(s, off);
    if ((tid & 63) == 0) wsum[tid >> 6] = s;
    __syncthreads();
    if (tid == 0) {
        float t = wsum[0] + wsum[1] + wsum[2] + wsum[3];
        out[0] = t * (1.0f / (float)N_PIX);
    }
}

extern "C" void kernel_launch(void* const* d_in, const int* in_sizes, int n_in,
                              void* d_out, int out_size, void* d_ws, size_t ws_size,
                              hipStream_t stream) {
    const float* z1 = (const float*)d_in[0];
    const float* z2 = (const float*)d_in[1];
    float* out = (float*)d_out;

    ushort* z1b   = (ushort*)d_ws;                        // 1 MB
    ushort* z2b   = z1b + (size_t)N_PIX * D;              // 1 MB
    float* ps     = (float*)(z2b + (size_t)N_PIX * D);    // 8192*8*4 = 256 KB
    float* rowval = ps + (size_t)N_PIX * NSEG;            // 32 KB

    knorm<<<64, 256, 0, stream>>>(z1, z2, z1b, z2b);
    dim3 g2(N_PIX / 64, NSEG);                            // (128, 8) = 1024 blocks
    ksim<<<g2, 256, 0, stream>>>(z1b, z2b, ps);
    kfinal<<<N_PIX / 256, 256, 0, stream>>>(z1b, z2b, ps, rowval);
    kreduce<<<1, 256, 0, stream>>>(rowval, out);
}

// Round 5
// 55.701 us; speedup vs baseline: 1.4541x; 1.4541x over previous
//
#include <hip/hip_runtime.h>
#include <math.h>

#define N_PIX 8192      // 2*64*64
#define D 64
#define HW 4096         // h*w
#define BSTRIDE 262144  // d*h*w
#define C1 14.4269504088896340736f   // 10 * log2(e); |dot| <= 1 so (dot-1)*C1 <= ~0
#define NSEG 32
#define SEGCOLS (N_PIX / NSEG)       // 256 cols per segment
#define GROUPS (SEGCOLS / 32)        // 8 groups of 32 cols (2 tiles) per segment

typedef __attribute__((ext_vector_type(8))) short short8;   // 8 bf16 = 4 VGPR
typedef __attribute__((ext_vector_type(4))) float f32x4;

__device__ inline ushort f2bf(float x) {   // fp32 -> bf16 RNE
    uint u = __float_as_uint(x);
    return (ushort)((u + 0x7FFFu + ((u >> 16) & 1u)) >> 16);
}
__device__ inline float bflo(uint u) { return __uint_as_float(u << 16); }
__device__ inline float bfhi(uint u) { return __uint_as_float(u & 0xFFFF0000u); }

// ---------- K1: transpose + L2-normalize -> bf16 rows (N,64); 2 threads/pixel ----------
__global__ __launch_bounds__(256) void knorm(const float* __restrict__ z1,
                                             const float* __restrict__ z2,
                                             ushort* __restrict__ z1b,
                                             ushort* __restrict__ z2b) {
    int gid = blockIdx.x * 256 + threadIdx.x;   // 0..32767
    int half = gid & 1;                          // channel half
    int pixg = gid >> 1;                         // 0..16383
    int t = pixg >> 13;
    int n = pixg & (N_PIX - 1);
    const float* src = t ? z2 : z1;
    ushort* dst = t ? z2b : z1b;
    int b = n >> 12;
    int p = n & 4095;
    const float* base = src + b * BSTRIDE + (half * 32) * HW + p;
    float v[32];
    float ss = 0.f;
#pragma unroll
    for (int c = 0; c < 32; ++c) { v[c] = base[c * HW]; ss += v[c] * v[c]; }
    ss += __shfl_xor(ss, 1);                     // pair (even,odd) holds full pixel
    float inv = 1.0f / fmaxf(sqrtf(ss), 1e-12f);
    uint* o = (uint*)(dst + (size_t)n * D + half * 32);
#pragma unroll
    for (int c2 = 0; c2 < 16; ++c2) {
        o[c2] = (uint)f2bf(v[2 * c2] * inv) | ((uint)f2bf(v[2 * c2 + 1] * inv) << 16);
    }
}

// ---------- K2: MFMA sim + fixed-shift exp accumulation ----------
// block = 256 thr = 4 waves; wave owns 32 rows; block covers 128 rows.
// grid (64 row-blocks, 32 col-segments) = 2048 blocks. All 4 waves share B (L1 reuse).
__global__ __launch_bounds__(256, 4) void ksim(const ushort* __restrict__ z1b,
                                               const ushort* __restrict__ z2b,
                                               float* __restrict__ ps) {
    int tid = threadIdx.x;
    int wave = tid >> 6, lane = tid & 63;
    int lrow = lane & 15;        // operand row within 16
    int lk = lane >> 4;          // k-chunk 0..3
    int rbase = blockIdx.x * 128 + wave * 32;
    int jbase = blockIdx.y * SEGCOLS;

    // A fragments: two row-tiles, fixed for whole kernel
    const ushort* ar0 = z1b + (size_t)(rbase + lrow) * D + lk * 8;
    short8 a00 = *(const short8*)ar0;
    short8 a01 = *(const short8*)(ar0 + 32);
    short8 a10 = *(const short8*)(ar0 + 16 * D);
    short8 a11 = *(const short8*)(ar0 + 16 * D + 32);

    float s0[4] = {0.f, 0.f, 0.f, 0.f};   // rows rbase + lk*4 + r
    float s1[4] = {0.f, 0.f, 0.f, 0.f};   // rows rbase + 16 + lk*4 + r

    const ushort* bbase = z2b + (size_t)(jbase + lrow) * D + lk * 8;
    short8 b00 = *(const short8*)(bbase);
    short8 b01 = *(const short8*)(bbase + 32);
    short8 b10 = *(const short8*)(bbase + 16 * D);
    short8 b11 = *(const short8*)(bbase + 16 * D + 32);

    for (int g = 0; g < GROUPS; ++g) {
        short8 n00 = b00, n01 = b01, n10 = b10, n11 = b11;
        if (g + 1 < GROUPS) {                     // register double-buffer prefetch
            const ushort* np = bbase + (size_t)(g + 1) * 32 * D;
            n00 = *(const short8*)(np);
            n01 = *(const short8*)(np + 32);
            n10 = *(const short8*)(np + 16 * D);
            n11 = *(const short8*)(np + 16 * D + 32);
        }
        f32x4 acc00 = {0.f, 0.f, 0.f, 0.f};
        f32x4 acc01 = {0.f, 0.f, 0.f, 0.f};
        f32x4 acc10 = {0.f, 0.f, 0.f, 0.f};
        f32x4 acc11 = {0.f, 0.f, 0.f, 0.f};
        acc00 = __builtin_amdgcn_mfma_f32_16x16x32_bf16(a00, b00, acc00, 0, 0, 0);
        acc01 = __builtin_amdgcn_mfma_f32_16x16x32_bf16(a00, b10, acc01, 0, 0, 0);
        acc10 = __builtin_amdgcn_mfma_f32_16x16x32_bf16(a10, b00, acc10, 0, 0, 0);
        acc11 = __builtin_amdgcn_mfma_f32_16x16x32_bf16(a10, b10, acc11, 0, 0, 0);
        acc00 = __builtin_amdgcn_mfma_f32_16x16x32_bf16(a01, b01, acc00, 0, 0, 0);
        acc01 = __builtin_amdgcn_mfma_f32_16x16x32_bf16(a01, b11, acc01, 0, 0, 0);
        acc10 = __builtin_amdgcn_mfma_f32_16x16x32_bf16(a11, b01, acc10, 0, 0, 0);
        acc11 = __builtin_amdgcn_mfma_f32_16x16x32_bf16(a11, b11, acc11, 0, 0, 0);
        // sum 2^{(dot-1)*C1}: 16 independent exp2 (TRANS pipe), bare v_exp_f32
#pragma unroll
        for (int r = 0; r < 4; ++r) {
            s0[r] += __builtin_amdgcn_exp2f(fmaf(acc00[r], C1, -C1));
            s0[r] += __builtin_amdgcn_exp2f(fmaf(acc01[r], C1, -C1));
            s1[r] += __builtin_amdgcn_exp2f(fmaf(acc10[r], C1, -C1));
            s1[r] += __builtin_amdgcn_exp2f(fmaf(acc11[r], C1, -C1));
        }
        b00 = n00; b01 = n01; b10 = n10; b11 = n11;
    }

    // reduce over 16 lanes sharing lk (different cols, same rows)
#pragma unroll
    for (int off = 1; off <= 8; off <<= 1) {
#pragma unroll
        for (int r = 0; r < 4; ++r) {
            s0[r] += __shfl_xor(s0[r], off);
            s1[r] += __shfl_xor(s1[r], off);
        }
    }
    if (lrow == 0) {
        int seg = blockIdx.y;
        int r0 = rbase + lk * 4;
#pragma unroll
        for (int r = 0; r < 4; ++r) {
            ps[(size_t)(r0 + r) * NSEG + seg] = s0[r];
            ps[(size_t)(r0 + 16 + r) * NSEG + seg] = s1[r];
        }
    }
}

// ---------- K3 (fused final): combine partials + diag + mean via atomic ----------
__global__ __launch_bounds__(256) void kfinal(const ushort* __restrict__ z1b,
                                              const ushort* __restrict__ z2b,
                                              const float* __restrict__ ps,
                                              float* __restrict__ out) {
    __shared__ float wsum[4];
    int tid = threadIdx.x;
    int row = blockIdx.x * 256 + tid;

    const f32x4* pp = (const f32x4*)(ps + (size_t)row * NSEG);
    float s = 0.f;
#pragma unroll
    for (int q = 0; q < NSEG / 4; ++q) {
        f32x4 v = pp[q];
        s += (v[0] + v[1]) + (v[2] + v[3]);
    }
    // lse = 10 + ln(s)
    const uint4* xp = (const uint4*)(z1b + (size_t)row * D);
    const uint4* yp = (const uint4*)(z2b + (size_t)row * D);
    float d = 0.f;
#pragma unroll
    for (int q = 0; q < 8; ++q) {
        uint4 x = xp[q], y = yp[q];
        d = fmaf(bflo(x.x), bflo(y.x), d); d = fmaf(bfhi(x.x), bfhi(y.x), d);
        d = fmaf(bflo(x.y), bflo(y.y), d); d = fmaf(bfhi(x.y), bfhi(y.y), d);
        d = fmaf(bflo(x.z), bflo(y.z), d); d = fmaf(bfhi(x.z), bfhi(y.z), d);
        d = fmaf(bflo(x.w), bflo(y.w), d); d = fmaf(bfhi(x.w), bfhi(y.w), d);
    }
    float val = 10.0f + __logf(s) - 10.0f * d;

#pragma unroll
    for (int off = 32; off > 0; off >>= 1) val += __shfl_down(val, off);
    if ((tid & 63) == 0) wsum[tid >> 6] = val;
    __syncthreads();
    if (tid == 0) {
        float t = (wsum[0] + wsum[1]) + (wsum[2] + wsum[3]);
        atomicAdd(out, t * (1.0f / (float)N_PIX));
    }
}

extern "C" void kernel_launch(void* const* d_in, const int* in_sizes, int n_in,
                              void* d_out, int out_size, void* d_ws, size_t ws_size,
                              hipStream_t stream) {
    const float* z1 = (const float*)d_in[0];
    const float* z2 = (const float*)d_in[1];
    float* out = (float*)d_out;

    ushort* z1b = (ushort*)d_ws;                        // 1 MB
    ushort* z2b = z1b + (size_t)N_PIX * D;              // 1 MB
    float* ps   = (float*)(z2b + (size_t)N_PIX * D);    // 8192*32*4 = 1 MB

    hipMemsetAsync(out, 0, sizeof(float), stream);
    knorm<<<128, 256, 0, stream>>>(z1, z2, z1b, z2b);
    dim3 g2(N_PIX / 128, NSEG);                         // (64, 32) = 2048 blocks
    ksim<<<g2, 256, 0, stream>>>(z1b, z2b, ps);
    kfinal<<<N_PIX / 256, 256, 0, stream>>>(z1b, z2b, ps, out);
}

// Round 6
// 53.502 us; speedup vs baseline: 1.5138x; 1.0411x over previous
//
#include <hip/hip_runtime.h>
#include <math.h>

#define N_PIX 8192      // 2*64*64
#define D 64
#define HW 4096         // h*w
#define BSTRIDE 262144  // d*h*w
#define C1 14.4269504088896340736f   // 10 * log2(e); |dot| <= 1 so (dot-1)*C1 <= ~0
#define NSEG 32
#define SEGCOLS (N_PIX / NSEG)       // 256 cols per segment
#define GROUPS (SEGCOLS / 32)        // 8 groups of 32 cols (2 col-tiles) per segment

typedef __attribute__((ext_vector_type(8))) short short8;   // 8 bf16 = 4 VGPR
typedef __attribute__((ext_vector_type(4))) float f32x4;

__device__ inline ushort f2bf(float x) {   // fp32 -> bf16 RNE
    uint u = __float_as_uint(x);
    return (ushort)((u + 0x7FFFu + ((u >> 16) & 1u)) >> 16);
}
__device__ inline float bflo(uint u) { return __uint_as_float(u << 16); }
__device__ inline float bfhi(uint u) { return __uint_as_float(u & 0xFFFF0000u); }

struct BSet { short8 b00, b01, b10, b11; };
struct Acc  { f32x4 a00, a01, a10, a11; };

__device__ inline void loadB(const ushort* p, BSet& b) {
    b.b00 = *(const short8*)(p);
    b.b01 = *(const short8*)(p + 32);
    b.b10 = *(const short8*)(p + 16 * D);
    b.b11 = *(const short8*)(p + 16 * D + 32);
}
__device__ inline void mfma8(const short8& a00, const short8& a01,
                             const short8& a10, const short8& a11,
                             const BSet& b, Acc& o) {
    f32x4 z = {0.f, 0.f, 0.f, 0.f};
    o.a00 = __builtin_amdgcn_mfma_f32_16x16x32_bf16(a00, b.b00, z, 0, 0, 0);
    o.a01 = __builtin_amdgcn_mfma_f32_16x16x32_bf16(a00, b.b10, z, 0, 0, 0);
    o.a10 = __builtin_amdgcn_mfma_f32_16x16x32_bf16(a10, b.b00, z, 0, 0, 0);
    o.a11 = __builtin_amdgcn_mfma_f32_16x16x32_bf16(a10, b.b10, z, 0, 0, 0);
    o.a00 = __builtin_amdgcn_mfma_f32_16x16x32_bf16(a01, b.b01, o.a00, 0, 0, 0);
    o.a01 = __builtin_amdgcn_mfma_f32_16x16x32_bf16(a01, b.b11, o.a01, 0, 0, 0);
    o.a10 = __builtin_amdgcn_mfma_f32_16x16x32_bf16(a11, b.b01, o.a10, 0, 0, 0);
    o.a11 = __builtin_amdgcn_mfma_f32_16x16x32_bf16(a11, b.b11, o.a11, 0, 0, 0);
}
__device__ inline void expacc(const Acc& acc, float* s0, float* s1) {
#pragma unroll
    for (int r = 0; r < 4; ++r) {
        s0[r] += __builtin_amdgcn_exp2f(fmaf(acc.a00[r], C1, -C1));
        s0[r] += __builtin_amdgcn_exp2f(fmaf(acc.a01[r], C1, -C1));
        s1[r] += __builtin_amdgcn_exp2f(fmaf(acc.a10[r], C1, -C1));
        s1[r] += __builtin_amdgcn_exp2f(fmaf(acc.a11[r], C1, -C1));
    }
}

// ---------- K1: transpose + L2-normalize -> bf16 rows (N,64); 2 threads/pixel ----------
__global__ __launch_bounds__(256) void knorm(const float* __restrict__ z1,
                                             const float* __restrict__ z2,
                                             ushort* __restrict__ z1b,
                                             ushort* __restrict__ z2b) {
    int gid = blockIdx.x * 256 + threadIdx.x;   // 0..32767
    int half = gid & 1;                          // channel half
    int pixg = gid >> 1;                         // 0..16383
    int t = pixg >> 13;
    int n = pixg & (N_PIX - 1);
    const float* src = t ? z2 : z1;
    ushort* dst = t ? z2b : z1b;
    int b = n >> 12;
    int p = n & 4095;
    const float* base = src + b * BSTRIDE + (half * 32) * HW + p;
    float v[32];
    float ss = 0.f;
#pragma unroll
    for (int c = 0; c < 32; ++c) { v[c] = base[c * HW]; ss += v[c] * v[c]; }
    ss += __shfl_xor(ss, 1);                     // pair (even,odd) holds full pixel
    float inv = 1.0f / fmaxf(sqrtf(ss), 1e-12f);
    uint* o = (uint*)(dst + (size_t)n * D + half * 32);
#pragma unroll
    for (int c2 = 0; c2 < 16; ++c2) {
        o[c2] = (uint)f2bf(v[2 * c2] * inv) | ((uint)f2bf(v[2 * c2 + 1] * inv) << 16);
    }
}

// ---------- K2: MFMA sim + pipelined fixed-shift exp accumulation ----------
// block = 256 thr = 4 waves; wave owns 32 rows, block 128 rows.
// grid (64 row-blocks, 32 col-segments) = 2048 blocks.
// Software pipeline: exp of group g-1 overlaps MFMA of group g; B double-buffered in regs.
__global__ __launch_bounds__(256) void ksim(const ushort* __restrict__ z1b,
                                            const ushort* __restrict__ z2b,
                                            float* __restrict__ ps) {
    int tid = threadIdx.x;
    int wave = tid >> 6, lane = tid & 63;
    int lrow = lane & 15;        // operand row within 16
    int lk = lane >> 4;          // k-chunk 0..3
    int rbase = blockIdx.x * 128 + wave * 32;
    int jbase = blockIdx.y * SEGCOLS;

    const ushort* ar0 = z1b + (size_t)(rbase + lrow) * D + lk * 8;
    short8 a00 = *(const short8*)ar0;
    short8 a01 = *(const short8*)(ar0 + 32);
    short8 a10 = *(const short8*)(ar0 + 16 * D);
    short8 a11 = *(const short8*)(ar0 + 16 * D + 32);

    const ushort* bbase = z2b + (size_t)(jbase + lrow) * D + lk * 8;
    const size_t GSTRIDE = (size_t)32 * D;

    float s0[4] = {0.f, 0.f, 0.f, 0.f};
    float s1[4] = {0.f, 0.f, 0.f, 0.f};

    BSet bA, bB;
    Acc accP, accC;

    loadB(bbase + 0 * GSTRIDE, bA);              // g0
    loadB(bbase + 1 * GSTRIDE, bB);              // g1
    mfma8(a00, a01, a10, a11, bA, accP);         // g0

    // iterations handle groups (g, g+1) for g = 1,3,5 ; tail handles g7
#pragma unroll
    for (int g = 1; g < GROUPS - 1; g += 2) {
        loadB(bbase + (size_t)(g + 1) * GSTRIDE, bA);   // fetch g+1
        mfma8(a00, a01, a10, a11, bB, accC);            // compute g
        expacc(accP, s0, s1);                           // exp g-1 (overlaps MFMA g)
        loadB(bbase + (size_t)(g + 2) * GSTRIDE, bB);   // fetch g+2
        mfma8(a00, a01, a10, a11, bA, accP);            // compute g+1
        expacc(accC, s0, s1);                           // exp g   (overlaps MFMA g+1)
    }
    mfma8(a00, a01, a10, a11, bB, accC);                // g7
    expacc(accP, s0, s1);                               // g6
    expacc(accC, s0, s1);                               // g7

    // reduce over 16 lanes sharing lk (different cols, same rows)
#pragma unroll
    for (int off = 1; off <= 8; off <<= 1) {
#pragma unroll
        for (int r = 0; r < 4; ++r) {
            s0[r] += __shfl_xor(s0[r], off);
            s1[r] += __shfl_xor(s1[r], off);
        }
    }
    if (lrow == 0) {
        int seg = blockIdx.y;
        int r0 = rbase + lk * 4;
#pragma unroll
        for (int r = 0; r < 4; ++r) {
            ps[(size_t)(r0 + r) * NSEG + seg] = s0[r];
            ps[(size_t)(r0 + 16 + r) * NSEG + seg] = s1[r];
        }
    }
}

// ---------- K3 (fused final): combine partials + diag + mean via atomic ----------
__global__ __launch_bounds__(256) void kfinal(const ushort* __restrict__ z1b,
                                              const ushort* __restrict__ z2b,
                                              const float* __restrict__ ps,
                                              float* __restrict__ out) {
    __shared__ float wsum[4];
    int tid = threadIdx.x;
    int row = blockIdx.x * 256 + tid;

    const f32x4* pp = (const f32x4*)(ps + (size_t)row * NSEG);
    float s = 0.f;
#pragma unroll
    for (int q = 0; q < NSEG / 4; ++q) {
        f32x4 v = pp[q];
        s += (v[0] + v[1]) + (v[2] + v[3]);
    }
    // lse = 10 + ln(s)
    const uint4* xp = (const uint4*)(z1b + (size_t)row * D);
    const uint4* yp = (const uint4*)(z2b + (size_t)row * D);
    float d = 0.f;
#pragma unroll
    for (int q = 0; q < 8; ++q) {
        uint4 x = xp[q], y = yp[q];
        d = fmaf(bflo(x.x), bflo(y.x), d); d = fmaf(bfhi(x.x), bfhi(y.x), d);
        d = fmaf(bflo(x.y), bflo(y.y), d); d = fmaf(bfhi(x.y), bfhi(y.y), d);
        d = fmaf(bflo(x.z), bflo(y.z), d); d = fmaf(bfhi(x.z), bfhi(y.z), d);
        d = fmaf(bflo(x.w), bflo(y.w), d); d = fmaf(bfhi(x.w), bfhi(y.w), d);
    }
    float val = 10.0f + __logf(s) - 10.0f * d;

#pragma unroll
    for (int off = 32; off > 0; off >>= 1) val += __shfl_down(val, off);
    if ((tid & 63) == 0) wsum[tid >> 6] = val;
    __syncthreads();
    if (tid == 0) {
        float t = (wsum[0] + wsum[1]) + (wsum[2] + wsum[3]);
        atomicAdd(out, t * (1.0f / (float)N_PIX));
    }
}

extern "C" void kernel_launch(void* const* d_in, const int* in_sizes, int n_in,
                              void* d_out, int out_size, void* d_ws, size_t ws_size,
                              hipStream_t stream) {
    const float* z1 = (const float*)d_in[0];
    const float* z2 = (const float*)d_in[1];
    float* out = (float*)d_out;

    ushort* z1b = (ushort*)d_ws;                        // 1 MB
    ushort* z2b = z1b + (size_t)N_PIX * D;              // 1 MB
    float* ps   = (float*)(z2b + (size_t)N_PIX * D);    // 8192*32*4 = 1 MB

    hipMemsetAsync(out, 0, sizeof(float), stream);
    knorm<<<128, 256, 0, stream>>>(z1, z2, z1b, z2b);
    dim3 g2(N_PIX / 128, NSEG);                         // (64, 32) = 2048 blocks
    ksim<<<g2, 256, 0, stream>>>(z1b, z2b, ps);
    kfinal<<<N_PIX / 256, 256, 0, stream>>>(z1b, z2b, ps, out);
}